// Round 2
// baseline (449.604 us; speedup 1.0000x reference)
//
#include <hip/hip_runtime.h>
#include <cstdint>
#include <cstddef>

// Problem constants
#define NCB   8
#define KC    1024
#define SDIM  64
#define LDIM  512          // NCB*SDIM
#define BATCH 8192
#define INV_TAU (1.0f/0.07f)

typedef __bf16 bf16_t;
typedef bf16_t bf16x8 __attribute__((ext_vector_type(8)));
typedef float  floatx4 __attribute__((ext_vector_type(4)));

__device__ __forceinline__ unsigned short f2bf(float f) {
    union { float f; unsigned int u; } c; c.f = f;
    unsigned int u = c.u;
    u += 0x7fffu + ((u >> 16) & 1u);   // round-to-nearest-even
    return (unsigned short)(u >> 16);
}

// ---------------------------------------------------------------------------
// K1: e2[n][k] = ||e_nk||^2 ; also zero the two accumulators (ws is poisoned
// 0xAA before every launch, so zero-init must happen inside a kernel).
// ---------------------------------------------------------------------------
__global__ void k_prep(const float* __restrict__ emb, float* __restrict__ e2,
                       float* __restrict__ accs) {
    int id = blockIdx.x * 256 + threadIdx.x;          // 0..8191 = n*K+k
    const float4* e4 = (const float4*)(emb + (size_t)id * SDIM);
    float s0=0.f,s1=0.f,s2=0.f,s3=0.f;
#pragma unroll
    for (int i=0;i<16;i++){ float4 v=e4[i];
        s0=fmaf(v.x,v.x,s0); s1=fmaf(v.y,v.y,s1);
        s2=fmaf(v.z,v.z,s2); s3=fmaf(v.w,v.w,s3); }
    e2[id] = (s0+s1)+(s2+s3);
    if (id==0){ accs[0]=0.f; accs[1]=0.f; }
}

// fp64 "relative distance" e2 - 2*z.e (z2 cancels in argmin ordering)
__device__ __forceinline__ double dist64d(const float* __restrict__ e,
                                          const float* __restrict__ zg) {
    double se=0.0, sz=0.0;
#pragma unroll 8
    for (int i=0;i<64;i++){ double ev=(double)e[i];
        se = fma(ev,ev,se); sz = fma(ev,(double)zg[i],sz); }
    return se - 2.0*sz;
}

// ---------------------------------------------------------------------------
// K2: per (b,n) argmin over K=1024 codes. Block = 256 threads, covers 128 b's;
// lo half (tid<128) scans codes 0..511, hi half 512..1023. Codes staged in
// LDS (broadcast reads). Top-2 tracked; if gap < 1e-2 re-rank top-2 in fp64.
// Then gather quant row, write indices (as float), accumulate commit sum.
// ---------------------------------------------------------------------------
__global__ __launch_bounds__(256) void
k_argmin(const float* __restrict__ z, const float* __restrict__ emb,
         const float* __restrict__ e2, float* __restrict__ out_q,
         float* __restrict__ out_idx, float* __restrict__ accs) {
    __shared__ float Ech[2][128*64];
    __shared__ float e2ch[2][128];
    __shared__ float m1s[256], m2s[256];
    __shared__ int   i1s[256], i2s[256];

    const int tid  = threadIdx.x;
    const int half = tid >> 7;          // 0: codes 0..511, 1: 512..1023
    const int lt   = tid & 127;
    const int n    = blockIdx.y;
    const int b    = blockIdx.x * 128 + lt;

    // z sub-vector for this (b,n) in registers
    float zr[64];
    const float4* z4 = (const float4*)(z + (size_t)b*LDIM + n*SDIM);
#pragma unroll
    for (int i=0;i<16;i++){ float4 v=z4[i];
        zr[4*i]=v.x; zr[4*i+1]=v.y; zr[4*i+2]=v.z; zr[4*i+3]=v.w; }

    const float* eb  = emb + (size_t)n*KC*SDIM;
    const float* e2n = e2  + n*KC;

    float b1=3.4e38f, b2=3.4e38f; int i1=0, i2=0;

    for (int c=0;c<4;c++){
        __syncthreads();
        const int kbase = half*512 + c*128;
        {   // stage this half's 128-code chunk (32 KB) cooperatively
            const float4* src = (const float4*)(eb + (size_t)kbase*SDIM);
            float4* dst = (float4*)(&Ech[half][0]);
#pragma unroll
            for (int j=0;j<16;j++) dst[lt + j*128] = src[lt + j*128];
            e2ch[half][lt] = e2n[kbase + lt];
        }
        __syncthreads();
        for (int kk=0;kk<128;kk++){
            const float4* ev = (const float4*)(&Ech[half][kk*64]); // broadcast
            float s0=0.f,s1=0.f,s2=0.f,s3=0.f;
#pragma unroll
            for (int i=0;i<16;i++){ float4 v=ev[i];
                s0=fmaf(v.x,zr[4*i  ],s0); s1=fmaf(v.y,zr[4*i+1],s1);
                s2=fmaf(v.z,zr[4*i+2],s2); s3=fmaf(v.w,zr[4*i+3],s3); }
            float dot  = (s0+s1)+(s2+s3);
            float dist = e2ch[half][kk] - 2.0f*dot;
            int   kidx = kbase + kk;
            if (dist < b1){ b2=b1; i2=i1; b1=dist; i1=kidx; }
            else if (dist < b2){ b2=dist; i2=kidx; }
        }
    }

    m1s[tid]=b1; m2s[tid]=b2; i1s[tid]=i1; i2s[tid]=i2;
    __syncthreads();

    if (tid < 128) {
        // merge lo/hi top-2 (strict <: tie keeps lower index = lo half)
        float h1=m1s[tid+128], h2=m2s[tid+128];
        int   j1=i1s[tid+128], j2=i2s[tid+128];
        if (h1 < b1){ b2=b1; i2=i1; b1=h1; i1=j1; }
        else if (h1 < b2){ b2=h1; i2=j1; }
        if (h2 < b2){ b2=h2; i2=j2; }

        if (b2 - b1 < 1e-2f) {   // near-tie: exact fp64 re-rank of top-2
            const float* zg = z + (size_t)b*LDIM + n*SDIM;
            double d1 = dist64d(eb + (size_t)i1*SDIM, zg);
            double d2 = dist64d(eb + (size_t)i2*SDIM, zg);
            if (d2 < d1 || (d2 == d1 && i2 < i1)) i1 = i2;
        }

        // gather quantized row, write, accumulate commit partial
        const float4* q4 = (const float4*)(eb + (size_t)i1*SDIM);
        float4* oq = (float4*)(out_q + (size_t)b*LDIM + n*SDIM);
        float cs = 0.f;
#pragma unroll
        for (int i=0;i<16;i++){
            float4 v = q4[i];
            oq[i] = v;
            float d0=v.x-zr[4*i], d1=v.y-zr[4*i+1];
            float d2=v.z-zr[4*i+2], d3=v.w-zr[4*i+3];
            cs += d0*d0 + d1*d1 + d2*d2 + d3*d3;
        }
        out_idx[b*NCB + n] = (float)i1;

        for (int off=32; off; off>>=1) cs += __shfl_down(cs, off);
        if ((tid & 63)==0) atomicAdd(&accs[0], cs);
    }
}

// ---------------------------------------------------------------------------
// K3: per-row L2 norms of z and quant, write normalized bf16 copies, diag.
// ---------------------------------------------------------------------------
__global__ __launch_bounds__(256) void
k_norm(const float* __restrict__ z, const float* __restrict__ q,
       unsigned short* __restrict__ zn, unsigned short* __restrict__ qn,
       float* __restrict__ diag) {
    const int b = blockIdx.x, tid = threadIdx.x;
    const size_t base = (size_t)b*LDIM;
    float z0=z[base+tid], z1=z[base+256+tid];
    float q0=q[base+tid], q1=q[base+256+tid];
    float sz=z0*z0+z1*z1, sq=q0*q0+q1*q1, sqz=q0*z0+q1*z1;
    for (int off=32; off; off>>=1){
        sz+=__shfl_down(sz,off); sq+=__shfl_down(sq,off); sqz+=__shfl_down(sqz,off);
    }
    __shared__ float red[3][4];
    __shared__ float bc[2];
    int w = tid>>6;
    if ((tid&63)==0){ red[0][w]=sz; red[1][w]=sq; red[2][w]=sqz; }
    __syncthreads();
    if (tid==0){
        float tz = red[0][0]+red[0][1]+red[0][2]+red[0][3];
        float tq = red[1][0]+red[1][1]+red[1][2]+red[1][3];
        float tz_q = red[2][0]+red[2][1]+red[2][2]+red[2][3];
        float inz = 1.0f/fmaxf(sqrtf(tz), 1e-12f);
        float inq = 1.0f/fmaxf(sqrtf(tq), 1e-12f);
        bc[0]=inz; bc[1]=inq;
        diag[b] = tz_q*inz*inq*INV_TAU;
    }
    __syncthreads();
    float inz=bc[0], inq=bc[1];
    zn[base+tid]     = f2bf(z0*inz);
    zn[base+256+tid] = f2bf(z1*inz);
    qn[base+tid]     = f2bf(q0*inq);
    qn[base+256+tid] = f2bf(q1*inq);
}

// ---------------------------------------------------------------------------
// K4: flash-style logsumexp of logits = qn · zn^T / TAU. Grid (64 row-tiles,
// 8 col-chunks of 1024). Block 256 = 4 waves in 2x2, each wave 64x64 via 4x4
// 16x16x32 bf16 MFMAs. Per 128x128 tile: online (M,S) per row; each
// (chunk, wave_n) writes its own partial slot (16 partials/row).
// LDS tiles padded to stride 72 (144 B) to break power-of-2 bank aliasing.
// ---------------------------------------------------------------------------
__global__ __launch_bounds__(256,2) void
k_logits(const unsigned short* __restrict__ qn, const unsigned short* __restrict__ zn,
         float* __restrict__ Mpart, float* __restrict__ Spart) {
    __shared__ unsigned short As[128*72];
    __shared__ unsigned short Bs[128*72];
    const int tid  = threadIdx.x;
    const int i0   = blockIdx.x * 128;
    const int chnk = blockIdx.y;
    const int wid  = tid >> 6, lane = tid & 63;
    const int wm = wid & 1, wn = wid >> 1;
    const int c  = lane & 15, qq = lane >> 4;

    float M[16], S[16];
#pragma unroll
    for (int i=0;i<16;i++){ M[i] = -3.0e38f; S[i] = 0.f; }

    for (int jt=0;jt<8;jt++){
        const int j0 = chnk*1024 + jt*128;
        floatx4 acc[4][4];
#pragma unroll
        for (int mt=0;mt<4;mt++)
#pragma unroll
            for (int nt=0;nt<4;nt++) acc[mt][nt] = (floatx4){0.f,0.f,0.f,0.f};

        for (int kk=0;kk<512;kk+=64){
            __syncthreads();
            // stage A-tile and B-tile: each 128 rows x 64 bf16 = 1024 x 16B
#pragma unroll
            for (int s=0;s<4;s++){
                int seg = tid + s*256;          // 0..1023
                int r = seg >> 3, sg = seg & 7;
                uint4 va = *(const uint4*)(qn + (size_t)(i0+r)*LDIM + kk + sg*8);
                *(uint4*)(&As[r*72 + sg*8]) = va;
            }
#pragma unroll
            for (int s=0;s<4;s++){
                int seg = tid + s*256;
                int r = seg >> 3, sg = seg & 7;
                uint4 vb = *(const uint4*)(zn + (size_t)(j0+r)*LDIM + kk + sg*8);
                *(uint4*)(&Bs[r*72 + sg*8]) = vb;
            }
            __syncthreads();
#pragma unroll
            for (int t=0;t<2;t++){
                bf16x8 af[4], bfr[4];
#pragma unroll
                for (int mt=0;mt<4;mt++)
                    af[mt]  = *(const bf16x8*)(&As[(wm*64+mt*16+c)*72 + t*32 + qq*8]);
#pragma unroll
                for (int nt=0;nt<4;nt++)
                    bfr[nt] = *(const bf16x8*)(&Bs[(wn*64+nt*16+c)*72 + t*32 + qq*8]);
#pragma unroll
                for (int mt=0;mt<4;mt++)
#pragma unroll
                    for (int nt=0;nt<4;nt++)
                        acc[mt][nt] = __builtin_amdgcn_mfma_f32_16x16x32_bf16(
                            af[mt], bfr[nt], acc[mt][nt], 0, 0, 0);
            }
        }

        // online row stats. C layout: row = qq*4+reg, col = c (per 16x16 tile)
#pragma unroll
        for (int mt=0;mt<4;mt++){
#pragma unroll
            for (int reg=0;reg<4;reg++){
                float lm = fmaxf(fmaxf(acc[mt][0][reg], acc[mt][1][reg]),
                                 fmaxf(acc[mt][2][reg], acc[mt][3][reg]));
#pragma unroll
                for (int off=1;off<16;off<<=1) lm = fmaxf(lm, __shfl_xor(lm, off));
                lm *= INV_TAU;
                float ls = 0.f;
#pragma unroll
                for (int nt=0;nt<4;nt++)
                    ls += expf(acc[mt][nt][reg]*INV_TAU - lm);
#pragma unroll
                for (int off=1;off<16;off<<=1) ls += __shfl_xor(ls, off);
                int idx = mt*4+reg;
                float Mo = M[idx];
                float Mn = fmaxf(Mo, lm);
                S[idx] = S[idx]*expf(Mo-Mn) + ls*expf(lm-Mn);
                M[idx] = Mn;
            }
        }
    }

    if (c == 0){
        const int p = chnk*2 + wn;             // 16 partial slots
#pragma unroll
        for (int mt=0;mt<4;mt++)
#pragma unroll
            for (int reg=0;reg<4;reg++){
                int row = i0 + wm*64 + mt*16 + qq*4 + reg;
                Mpart[p*BATCH + row] = M[mt*4+reg];
                Spart[p*BATCH + row] = S[mt*4+reg];
            }
    }
}

// ---------------------------------------------------------------------------
// K5: combine the 16 partials per row -> LSE - diag, reduce to accs[1].
// ---------------------------------------------------------------------------
__global__ __launch_bounds__(256) void
k_finalize(const float* __restrict__ Mpart, const float* __restrict__ Spart,
           const float* __restrict__ diag, float* __restrict__ accs) {
    int r = blockIdx.x*256 + threadIdx.x;
    float M = -3.0e38f;
#pragma unroll
    for (int p=0;p<16;p++) M = fmaxf(M, Mpart[p*BATCH + r]);
    float Ssum = 0.f;
#pragma unroll
    for (int p=0;p<16;p++) Ssum += Spart[p*BATCH + r]*expf(Mpart[p*BATCH + r] - M);
    float val = M + logf(Ssum) - diag[r];
    for (int off=32; off; off>>=1) val += __shfl_down(val, off);
    if ((threadIdx.x & 63)==0) atomicAdd(&accs[1], val);
}

// K6: scalars
__global__ void k_write(const float* __restrict__ accs, float* __restrict__ out_s) {
    out_s[0] = 2.0f*accs[0] / (float)((size_t)BATCH*LDIM);   // commit+embed
    out_s[1] = accs[1] / (float)BATCH;                       // contrastive
}

// ---------------------------------------------------------------------------
extern "C" void kernel_launch(void* const* d_in, const int* in_sizes, int n_in,
                              void* d_out, int out_size, void* d_ws, size_t ws_size,
                              hipStream_t stream) {
    const float* z   = (const float*)d_in[0];   // (B, L)
    const float* emb = (const float*)d_in[1];   // (NC, K, SD)
    float* out = (float*)d_out;
    float* out_q       = out;                   // B*L = 4194304
    float* out_scalars = out + 4194304;         // [commit, contrastive]
    float* out_idx     = out + 4194306;         // B*NC as float

    // ws layout (float offsets); total ~17.9 MB
    float* wsf   = (float*)d_ws;
    float* e2    = wsf;                         // 8192
    float* accs  = wsf + 8192;                  // 2 (commit, contrastive)
    float* diag  = wsf + 8704;                  // 8192
    float* Mpart = wsf + 16896;                 // 16*8192
    float* Spart = Mpart + 16*BATCH;            // 16*8192
    unsigned short* qn = (unsigned short*)(Spart + 16*BATCH);  // B*L bf16
    unsigned short* zn = qn + (size_t)BATCH*LDIM;              // B*L bf16

    k_prep   <<<32,          256, 0, stream>>>(emb, e2, accs);
    k_argmin <<<dim3(64,8),  256, 0, stream>>>(z, emb, e2, out_q, out_idx, accs);
    k_norm   <<<BATCH,       256, 0, stream>>>(z, out_q, zn, qn, diag);
    k_logits <<<dim3(64,8),  256, 0, stream>>>(qn, zn, Mpart, Spart);
    k_finalize<<<32,         256, 0, stream>>>(Mpart, Spart, diag, accs);
    k_write  <<<1,           1,   0, stream>>>(accs, out_scalars);
}

// Round 3
// 282.701 us; speedup vs baseline: 1.5904x; 1.5904x over previous
//
#include <hip/hip_runtime.h>
#include <cstdint>
#include <cstddef>

// Problem constants
#define NCB   8
#define KC    1024
#define SDIM  64
#define LDIM  512          // NCB*SDIM
#define BATCH 8192
#define INV_TAU (1.0f/0.07f)

typedef __bf16 bf16_t;
typedef bf16_t bf16x8 __attribute__((ext_vector_type(8)));
typedef float  floatx4 __attribute__((ext_vector_type(4)));

__device__ __forceinline__ unsigned short f2bf(float f) {
    union { float f; unsigned int u; } c; c.f = f;
    unsigned int u = c.u;
    u += 0x7fffu + ((u >> 16) & 1u);   // round-to-nearest-even
    return (unsigned short)(u >> 16);
}
__device__ __forceinline__ float bf2f(unsigned short h) {
    union { unsigned int u; float f; } c; c.u = ((unsigned int)h) << 16;
    return c.f;
}

// merge two sorted top-2 lists (m1<=m2, o1<=o2) -> top-2
__device__ __forceinline__ void merge2(float& m1, int& i1, float& m2, int& i2,
                                       float o1, int j1, float o2, int j2) {
    bool a = o1 < m1;
    float f1 = a ? o1 : m1; int g1 = a ? j1 : i1;
    float f2 = a ? m1 : o1; int g2 = a ? i1 : j1;
    bool b = o2 < m2;
    float f3 = b ? o2 : m2; int g3 = b ? j2 : i2;
    bool c = f3 < f2;
    m1 = f1; i1 = g1;
    m2 = c ? f3 : f2; i2 = c ? g3 : g2;
}

// ---------------------------------------------------------------------------
// K1: e2[n][k] = ||e_nk||^2 ; bf16 hi/lo split of embeddings; zero accs.
// ---------------------------------------------------------------------------
__global__ void k_prep(const float* __restrict__ emb, float* __restrict__ e2,
                       unsigned short* __restrict__ eh, unsigned short* __restrict__ el,
                       float* __restrict__ accs) {
    int id = blockIdx.x * 256 + threadIdx.x;          // 0..8191 = n*K+k
    const float4* e4 = (const float4*)(emb + (size_t)id * SDIM);
    ushort4* eh4 = (ushort4*)(eh + (size_t)id * SDIM);
    ushort4* el4 = (ushort4*)(el + (size_t)id * SDIM);
    float s0=0.f,s1=0.f,s2=0.f,s3=0.f;
#pragma unroll
    for (int i=0;i<16;i++){ float4 v=e4[i];
        s0=fmaf(v.x,v.x,s0); s1=fmaf(v.y,v.y,s1);
        s2=fmaf(v.z,v.z,s2); s3=fmaf(v.w,v.w,s3);
        ushort4 h, l;
        h.x=f2bf(v.x); l.x=f2bf(v.x-bf2f(h.x));
        h.y=f2bf(v.y); l.y=f2bf(v.y-bf2f(h.y));
        h.z=f2bf(v.z); l.z=f2bf(v.z-bf2f(h.z));
        h.w=f2bf(v.w); l.w=f2bf(v.w-bf2f(h.w));
        eh4[i]=h; el4[i]=l;
    }
    e2[id] = (s0+s1)+(s2+s3);
    if (id==0){ accs[0]=0.f; accs[1]=0.f; }
}

// K1b: bf16 hi/lo split of z (one float4 per thread)
__global__ void k_castz(const float* __restrict__ z,
                        unsigned short* __restrict__ zh, unsigned short* __restrict__ zl) {
    int id = blockIdx.x * 256 + threadIdx.x;          // handles 4 floats
    float4 v = ((const float4*)z)[id];
    ushort4 h, l;
    h.x=f2bf(v.x); l.x=f2bf(v.x-bf2f(h.x));
    h.y=f2bf(v.y); l.y=f2bf(v.y-bf2f(h.y));
    h.z=f2bf(v.z); l.z=f2bf(v.z-bf2f(h.z));
    h.w=f2bf(v.w); l.w=f2bf(v.w-bf2f(h.w));
    ((ushort4*)zh)[id]=h; ((ushort4*)zl)[id]=l;
}

// fp64 "relative distance" e2 - 2*z.e (z2 cancels in argmin ordering)
__device__ __forceinline__ double dist64d(const float* __restrict__ e,
                                          const float* __restrict__ zg) {
    double se=0.0, sz=0.0;
#pragma unroll 8
    for (int i=0;i<64;i++){ double ev=(double)e[i];
        se = fma(ev,ev,se); sz = fma(ev,(double)zg[i],sz); }
    return se - 2.0*sz;
}

// ---------------------------------------------------------------------------
// K2: MFMA argmin. Per block: 128 z-rows (one codebook n), all 1024 codes in
// 16 j-tiles of 64. cross via split-bf16: zh*eh + zh*el + zl*eh (3 MFMAs),
// error ~1e-3 << 2e-2 fp64 re-rank trigger. Per-lane running top-2 over its
// 16 C-rows; butterfly merge over the 16 col-lanes at the end; cross-wave
// merge via LDS; tail = fp64 refine + gather + commit (R2-verified).
// A/B tiles padded to stride 72 shorts (144 B) — conflict-free frag reads.
// ---------------------------------------------------------------------------
__global__ __launch_bounds__(256,2) void
k_argmin(const unsigned short* __restrict__ zh, const unsigned short* __restrict__ zl,
         const unsigned short* __restrict__ eh, const unsigned short* __restrict__ el,
         const float* __restrict__ e2, const float* __restrict__ z,
         const float* __restrict__ emb, float* __restrict__ out_q,
         float* __restrict__ out_idx, float* __restrict__ accs) {
    __shared__ unsigned short Ah[128*72], Al[128*72];
    __shared__ unsigned short Bh[64*72],  Bl[64*72];
    __shared__ float e2s[64];
    __shared__ float mM[2][128][2];
    __shared__ int   mI[2][128][2];

    const int tid = threadIdx.x;
    const int n   = blockIdx.y;
    const int i0  = blockIdx.x * 128;
    const int wid = tid >> 6, lane = tid & 63;
    const int wm = wid & 1, wn = wid >> 1;
    const int c  = lane & 15, qq = lane >> 4;

    // stage A (resident): 128 rows x 64 bf16, hi+lo
#pragma unroll
    for (int s=0;s<4;s++){
        int seg = tid + s*256; int r = seg>>3, sg = seg&7;
        size_t go = (size_t)(i0+r)*LDIM + n*SDIM + sg*8;
        *(uint4*)(&Ah[r*72+sg*8]) = *(const uint4*)(zh + go);
        *(uint4*)(&Al[r*72+sg*8]) = *(const uint4*)(zl + go);
    }

    float m1[16], m2[16]; int i1v[16], i2v[16];
#pragma unroll
    for (int j=0;j<16;j++){ m1[j]=3.4e38f; m2[j]=3.4e38f; i1v[j]=0; i2v[j]=0; }

    const unsigned short* ehn = eh + (size_t)n*KC*SDIM;
    const unsigned short* eln = el + (size_t)n*KC*SDIM;
    const float* e2n = e2 + n*KC;

    for (int jt=0; jt<16; jt++){
        const int j0 = jt*64;
        __syncthreads();
#pragma unroll
        for (int s=0;s<2;s++){        // stage B: 64 codes x 64 bf16, hi+lo
            int seg = tid + s*256; int r = seg>>3, sg = seg&7;
            size_t go = (size_t)(j0+r)*SDIM + sg*8;
            *(uint4*)(&Bh[r*72+sg*8]) = *(const uint4*)(ehn + go);
            *(uint4*)(&Bl[r*72+sg*8]) = *(const uint4*)(eln + go);
        }
        if (tid < 64) e2s[tid] = e2n[j0+tid];
        __syncthreads();

        floatx4 acc[4][2];
#pragma unroll
        for (int mt=0;mt<4;mt++)
#pragma unroll
            for (int nt=0;nt<2;nt++) acc[mt][nt] = (floatx4){0.f,0.f,0.f,0.f};

#pragma unroll
        for (int t=0;t<2;t++){
            bf16x8 ah[4], al[4], bh[2], bl[2];
#pragma unroll
            for (int mt=0;mt<4;mt++){
                ah[mt] = *(const bf16x8*)(&Ah[(wm*64+mt*16+c)*72 + t*32 + qq*8]);
                al[mt] = *(const bf16x8*)(&Al[(wm*64+mt*16+c)*72 + t*32 + qq*8]);
            }
#pragma unroll
            for (int nt=0;nt<2;nt++){
                bh[nt] = *(const bf16x8*)(&Bh[(wn*32+nt*16+c)*72 + t*32 + qq*8]);
                bl[nt] = *(const bf16x8*)(&Bl[(wn*32+nt*16+c)*72 + t*32 + qq*8]);
            }
#pragma unroll
            for (int mt=0;mt<4;mt++)
#pragma unroll
                for (int nt=0;nt<2;nt++){
                    acc[mt][nt] = __builtin_amdgcn_mfma_f32_16x16x32_bf16(ah[mt], bh[nt], acc[mt][nt], 0,0,0);
                    acc[mt][nt] = __builtin_amdgcn_mfma_f32_16x16x32_bf16(ah[mt], bl[nt], acc[mt][nt], 0,0,0);
                    acc[mt][nt] = __builtin_amdgcn_mfma_f32_16x16x32_bf16(al[mt], bh[nt], acc[mt][nt], 0,0,0);
                }
        }

        // dist = e2 - 2*cross ; per-lane running top-2 per row-slot
        const int colb = wn*32 + c;
#pragma unroll
        for (int nt=0;nt<2;nt++){
            float e2v = e2s[colb + nt*16];
            int kidx = j0 + colb + nt*16;
#pragma unroll
            for (int mt=0;mt<4;mt++)
#pragma unroll
                for (int reg=0;reg<4;reg++){
                    float d = fmaf(-2.0f, acc[mt][nt][reg], e2v);
                    int s = mt*4+reg;
                    float om1 = m1[s]; int oi1 = i1v[s];
                    bool lt1 = d < om1;
                    bool lt2 = d < m2[s];
                    m2[s]  = lt1 ? om1 : (lt2 ? d : m2[s]);
                    i2v[s] = lt1 ? oi1 : (lt2 ? kidx : i2v[s]);
                    m1[s]  = lt1 ? d : om1;
                    i1v[s] = lt1 ? kidx : oi1;
                }
        }
    }

    // butterfly top-2 merge across the 16 col-lanes (same rows, disjoint cols)
#pragma unroll
    for (int off=1; off<16; off<<=1){
#pragma unroll
        for (int s=0;s<16;s++){
            float o1 = __shfl_xor(m1[s], off);
            float o2 = __shfl_xor(m2[s], off);
            int   j1 = __shfl_xor(i1v[s], off);
            int   j2 = __shfl_xor(i2v[s], off);
            merge2(m1[s], i1v[s], m2[s], i2v[s], o1, j1, o2, j2);
        }
    }
    if (c == 0){
#pragma unroll
        for (int s=0;s<16;s++){
            int row = wm*64 + (s>>2)*16 + qq*4 + (s&3);
            mM[wn][row][0] = m1[s]; mM[wn][row][1] = m2[s];
            mI[wn][row][0] = i1v[s]; mI[wn][row][1] = i2v[s];
        }
    }
    __syncthreads();

    if (tid < 128){
        int b = i0 + tid;
        float b1 = mM[0][tid][0], b2v = mM[0][tid][1];
        int  ii1 = mI[0][tid][0], ii2 = mI[0][tid][1];
        merge2(b1, ii1, b2v, ii2, mM[1][tid][0], mI[1][tid][0],
                                  mM[1][tid][1], mI[1][tid][1]);

        const float* eb = emb + (size_t)n*KC*SDIM;
        const float* zg = z + (size_t)b*LDIM + n*SDIM;
        if (b2v - b1 < 2e-2f) {   // near-tie: exact fp64 re-rank of top-2
            double d1 = dist64d(eb + (size_t)ii1*SDIM, zg);
            double d2 = dist64d(eb + (size_t)ii2*SDIM, zg);
            if (d2 < d1 || (d2 == d1 && ii2 < ii1)) ii1 = ii2;
        }

        const float4* q4 = (const float4*)(eb + (size_t)ii1*SDIM);
        const float4* z4 = (const float4*)zg;
        float4* oq = (float4*)(out_q + (size_t)b*LDIM + n*SDIM);
        float cs = 0.f;
#pragma unroll
        for (int i=0;i<16;i++){
            float4 v = q4[i]; float4 zv = z4[i];
            oq[i] = v;
            float d0=v.x-zv.x, d1=v.y-zv.y, d2=v.z-zv.z, d3=v.w-zv.w;
            cs += d0*d0 + d1*d1 + d2*d2 + d3*d3;
        }
        out_idx[b*NCB + n] = (float)ii1;

        for (int off=32; off; off>>=1) cs += __shfl_down(cs, off);
        if ((tid & 63)==0) atomicAdd(&accs[0], cs);
    }
}

// ---------------------------------------------------------------------------
// K3: per-row L2 norms of z and quant, write normalized bf16 copies, diag.
// ---------------------------------------------------------------------------
__global__ __launch_bounds__(256) void
k_norm(const float* __restrict__ z, const float* __restrict__ q,
       unsigned short* __restrict__ zn, unsigned short* __restrict__ qn,
       float* __restrict__ diag) {
    const int b = blockIdx.x, tid = threadIdx.x;
    const size_t base = (size_t)b*LDIM;
    float z0=z[base+tid], z1=z[base+256+tid];
    float q0=q[base+tid], q1=q[base+256+tid];
    float sz=z0*z0+z1*z1, sq=q0*q0+q1*q1, sqz=q0*z0+q1*z1;
    for (int off=32; off; off>>=1){
        sz+=__shfl_down(sz,off); sq+=__shfl_down(sq,off); sqz+=__shfl_down(sqz,off);
    }
    __shared__ float red[3][4];
    __shared__ float bc[2];
    int w = tid>>6;
    if ((tid&63)==0){ red[0][w]=sz; red[1][w]=sq; red[2][w]=sqz; }
    __syncthreads();
    if (tid==0){
        float tz = red[0][0]+red[0][1]+red[0][2]+red[0][3];
        float tq = red[1][0]+red[1][1]+red[1][2]+red[1][3];
        float tz_q = red[2][0]+red[2][1]+red[2][2]+red[2][3];
        float inz = 1.0f/fmaxf(sqrtf(tz), 1e-12f);
        float inq = 1.0f/fmaxf(sqrtf(tq), 1e-12f);
        bc[0]=inz; bc[1]=inq;
        diag[b] = tz_q*inz*inq*INV_TAU;
    }
    __syncthreads();
    float inz=bc[0], inq=bc[1];
    zn[base+tid]     = f2bf(z0*inz);
    zn[base+256+tid] = f2bf(z1*inz);
    qn[base+tid]     = f2bf(q0*inq);
    qn[base+256+tid] = f2bf(q1*inq);
}

// ---------------------------------------------------------------------------
// K4: flash-style logsumexp of logits = qn · zn^T / TAU. (unchanged from R2)
// ---------------------------------------------------------------------------
__global__ __launch_bounds__(256,2) void
k_logits(const unsigned short* __restrict__ qn, const unsigned short* __restrict__ zn,
         float* __restrict__ Mpart, float* __restrict__ Spart) {
    __shared__ unsigned short As[128*72];
    __shared__ unsigned short Bs[128*72];
    const int tid  = threadIdx.x;
    const int i0   = blockIdx.x * 128;
    const int chnk = blockIdx.y;
    const int wid  = tid >> 6, lane = tid & 63;
    const int wm = wid & 1, wn = wid >> 1;
    const int c  = lane & 15, qq = lane >> 4;

    float M[16], S[16];
#pragma unroll
    for (int i=0;i<16;i++){ M[i] = -3.0e38f; S[i] = 0.f; }

    for (int jt=0;jt<8;jt++){
        const int j0 = chnk*1024 + jt*128;
        floatx4 acc[4][4];
#pragma unroll
        for (int mt=0;mt<4;mt++)
#pragma unroll
            for (int nt=0;nt<4;nt++) acc[mt][nt] = (floatx4){0.f,0.f,0.f,0.f};

        for (int kk=0;kk<512;kk+=64){
            __syncthreads();
#pragma unroll
            for (int s=0;s<4;s++){
                int seg = tid + s*256;
                int r = seg >> 3, sg = seg & 7;
                uint4 va = *(const uint4*)(qn + (size_t)(i0+r)*LDIM + kk + sg*8);
                *(uint4*)(&As[r*72 + sg*8]) = va;
            }
#pragma unroll
            for (int s=0;s<4;s++){
                int seg = tid + s*256;
                int r = seg >> 3, sg = seg & 7;
                uint4 vb = *(const uint4*)(zn + (size_t)(j0+r)*LDIM + kk + sg*8);
                *(uint4*)(&Bs[r*72 + sg*8]) = vb;
            }
            __syncthreads();
#pragma unroll
            for (int t=0;t<2;t++){
                bf16x8 af[4], bfr[4];
#pragma unroll
                for (int mt=0;mt<4;mt++)
                    af[mt]  = *(const bf16x8*)(&As[(wm*64+mt*16+c)*72 + t*32 + qq*8]);
#pragma unroll
                for (int nt=0;nt<4;nt++)
                    bfr[nt] = *(const bf16x8*)(&Bs[(wn*64+nt*16+c)*72 + t*32 + qq*8]);
#pragma unroll
                for (int mt=0;mt<4;mt++)
#pragma unroll
                    for (int nt=0;nt<4;nt++)
                        acc[mt][nt] = __builtin_amdgcn_mfma_f32_16x16x32_bf16(
                            af[mt], bfr[nt], acc[mt][nt], 0, 0, 0);
            }
        }

#pragma unroll
        for (int mt=0;mt<4;mt++){
#pragma unroll
            for (int reg=0;reg<4;reg++){
                float lm = fmaxf(fmaxf(acc[mt][0][reg], acc[mt][1][reg]),
                                 fmaxf(acc[mt][2][reg], acc[mt][3][reg]));
#pragma unroll
                for (int off=1;off<16;off<<=1) lm = fmaxf(lm, __shfl_xor(lm, off));
                lm *= INV_TAU;
                float ls = 0.f;
#pragma unroll
                for (int nt=0;nt<4;nt++)
                    ls += expf(acc[mt][nt][reg]*INV_TAU - lm);
#pragma unroll
                for (int off=1;off<16;off<<=1) ls += __shfl_xor(ls, off);
                int idx = mt*4+reg;
                float Mo = M[idx];
                float Mn = fmaxf(Mo, lm);
                S[idx] = S[idx]*expf(Mo-Mn) + ls*expf(lm-Mn);
                M[idx] = Mn;
            }
        }
    }

    if (c == 0){
        const int p = chnk*2 + wn;
#pragma unroll
        for (int mt=0;mt<4;mt++)
#pragma unroll
            for (int reg=0;reg<4;reg++){
                int row = i0 + wm*64 + mt*16 + qq*4 + reg;
                Mpart[p*BATCH + row] = M[mt*4+reg];
                Spart[p*BATCH + row] = S[mt*4+reg];
            }
    }
}

// ---------------------------------------------------------------------------
// K5: combine the 16 partials per row -> LSE - diag, reduce to accs[1].
// ---------------------------------------------------------------------------
__global__ __launch_bounds__(256) void
k_finalize(const float* __restrict__ Mpart, const float* __restrict__ Spart,
           const float* __restrict__ diag, float* __restrict__ accs) {
    int r = blockIdx.x*256 + threadIdx.x;
    float M = -3.0e38f;
#pragma unroll
    for (int p=0;p<16;p++) M = fmaxf(M, Mpart[p*BATCH + r]);
    float Ssum = 0.f;
#pragma unroll
    for (int p=0;p<16;p++) Ssum += Spart[p*BATCH + r]*expf(Mpart[p*BATCH + r] - M);
    float val = M + logf(Ssum) - diag[r];
    for (int off=32; off; off>>=1) val += __shfl_down(val, off);
    if ((threadIdx.x & 63)==0) atomicAdd(&accs[1], val);
}

// K6: scalars
__global__ void k_write(const float* __restrict__ accs, float* __restrict__ out_s) {
    out_s[0] = 2.0f*accs[0] / (float)((size_t)BATCH*LDIM);   // commit+embed
    out_s[1] = accs[1] / (float)BATCH;                       // contrastive
}

// ---------------------------------------------------------------------------
extern "C" void kernel_launch(void* const* d_in, const int* in_sizes, int n_in,
                              void* d_out, int out_size, void* d_ws, size_t ws_size,
                              hipStream_t stream) {
    const float* z   = (const float*)d_in[0];   // (B, L)
    const float* emb = (const float*)d_in[1];   // (NC, K, SD)
    float* out = (float*)d_out;
    float* out_q       = out;                   // B*L = 4194304
    float* out_scalars = out + 4194304;         // [commit, contrastive]
    float* out_idx     = out + 4194306;         // B*NC as float

    // ws layout (float offsets); ~20 MB total
    float* wsf   = (float*)d_ws;
    float* e2    = wsf;                         // 8192
    float* accs  = wsf + 8192;                  // 2
    float* diag  = wsf + 8704;                  // 8192
    float* Mpart = wsf + 16896;                 // 16*8192
    float* Spart = Mpart + 16*BATCH;            // 16*8192
    unsigned short* qn = (unsigned short*)(Spart + 16*BATCH);  // B*L bf16
    unsigned short* zn = qn + (size_t)BATCH*LDIM;              // B*L bf16
    unsigned short* eh = zn + (size_t)BATCH*LDIM;              // NC*K*SD bf16
    unsigned short* el = eh + (size_t)NCB*KC*SDIM;             // NC*K*SD bf16
    // zh/zl alias qn/zn: argmin (reader) completes before k_norm overwrites.
    unsigned short* zhp = qn;
    unsigned short* zlp = zn;

    k_prep   <<<32,          256, 0, stream>>>(emb, e2, eh, el, accs);
    k_castz  <<<4096,        256, 0, stream>>>(z, zhp, zlp);
    k_argmin <<<dim3(64,8),  256, 0, stream>>>(zhp, zlp, eh, el, e2, z, emb,
                                               out_q, out_idx, accs);
    k_norm   <<<BATCH,       256, 0, stream>>>(z, out_q, zn, qn, diag);
    k_logits <<<dim3(64,8),  256, 0, stream>>>(qn, zn, Mpart, Spart);
    k_finalize<<<32,         256, 0, stream>>>(Mpart, Spart, diag, accs);
    k_write  <<<1,           1,   0, stream>>>(accs, out_scalars);
}